// Round 1
// baseline (177.348 us; speedup 1.0000x reference)
//
#include <hip/hip_runtime.h>
#include <math.h>

#define S2D   384
#define NB    64
#define NPTS  8192
#define GRID_W 128

// Per-point lattice computation, faithful to the reference fp32 semantics:
//  - elevated: fma-ascending 3-term dot (XLA/BLAS-style accumulation)
//  - greedy: rintf (round-half-even, == jnp.round) of correctly-rounded div by 3
//  - rank: stable descending rank among the 3 residuals
//  - shift/remainder bookkeeping exactly as in reference; only channels 0,1 needed
__device__ __forceinline__ void compute_point(const float* __restrict__ pc1,
                                              const float* __restrict__ tm,
                                              int b, int n,
                                              int& gi0, int& gi1, int& r0, int& r1) {
    const float p0 = pc1[((size_t)b * 3 + 0) * NPTS + n];
    const float p1 = pc1[((size_t)b * 3 + 1) * NPTS + n];
    const float p2 = pc1[((size_t)b * 3 + 2) * NPTS + n];
    const float* t = tm + b * 9;

    float g[3], v[3];
#pragma unroll
    for (int i = 0; i < 3; i++) {
        // e = t[i][0]*p0 + t[i][1]*p1 + t[i][2]*p2, fma chain ascending j
        float e = fmaf(t[i * 3 + 2], p2, fmaf(t[i * 3 + 1], p1, t[i * 3 + 0] * p0));
        float q = __fdiv_rn(e, 3.0f);     // correctly-rounded fp32 div (matches x/3)
        g[i] = rintf(q) * 3.0f;           // exact: |round| <= ~200, *3 exact in fp32
        v[i] = e - g[i];                  // exact (Sterbenz)
    }

    int rank[3];
#pragma unroll
    for (int i = 0; i < 3; i++) {
        int r = 0;
#pragma unroll
        for (int j = 0; j < 3; j++) {
            // stable descending argsort -> inverse perm:
            // rank[i] = #{j: v[j] > v[i]} + #{j < i: v[j] == v[i]}
            if (v[j] > v[i] || (v[j] == v[i] && j < i)) r++;
        }
        rank[i] = r;
    }

    const float rs_f = __fdiv_rn(g[0] + g[1] + g[2], 3.0f);  // exact integer value
    const int   rs   = (int)rs_f;

#pragma unroll
    for (int i = 0; i < 2; i++) {   // only lattice channels 0,1 feed the output
        const float rank_f = (float)rank[i];
        const bool cond = ((rank_f >= 3.0f - rs_f) && (rs_f > 0.0f)) ||
                          ((rank_f <  -rs_f)       && (rs_f < 0.0f));
        const float sign  = (rs_f > 0.0f ? -1.0f : 0.0f) + (rs_f < 0.0f ? 1.0f : 0.0f);
        const float shift = 3.0f * sign * (cond ? 1.0f : 0.0f);
        g[i]    += shift;
        rank[i] += (int)shift + rs;
    }

    gi0 = (int)g[0];
    gi1 = (int)g[1];
    r0  = rank[0];
    r1  = rank[1];
}

// Pass A: per-batch min over n of (gi_c - clamp(rank_c,0,2)) for c=0,1.
// (CANONICAL row mins are {0,-1,-2} for clamped rank 0,1,2; JAX gather clamps.)
__global__ __launch_bounds__(256) void offsets_kernel(const float* __restrict__ pc1,
                                                      const float* __restrict__ tm,
                                                      int* __restrict__ offs) {
    const int n = blockIdx.x * blockDim.x + threadIdx.x;
    const int b = blockIdx.y;
    int gi0, gi1, r0, r1;
    compute_point(pc1, tm, b, n, gi0, gi1, r0, r1);

    int m0 = gi0 - min(max(r0, 0), 2);
    int m1 = gi1 - min(max(r1, 0), 2);

    // wave64 min-reduction
#pragma unroll
    for (int off = 32; off > 0; off >>= 1) {
        m0 = min(m0, __shfl_down(m0, off));
        m1 = min(m1, __shfl_down(m1, off));
    }
    if ((threadIdx.x & 63) == 0) {
        atomicMin(&offs[b * 2 + 0], m0);
        atomicMin(&offs[b * 2 + 1], m1);
    }
}

// Pass B: recompute gi, bounds-check against the dense 384 grid, scatter-add
// features directly into the strided 128x128 sub-grid (provably aligned).
__global__ __launch_bounds__(256) void splat_kernel(const float* __restrict__ pc1,
                                                    const float* __restrict__ feat,
                                                    const float* __restrict__ tm,
                                                    const int* __restrict__ offs,
                                                    float* __restrict__ out) {
    const int n = blockIdx.x * blockDim.x + threadIdx.x;
    const int b = blockIdx.y;
    int gi0, gi1, r0, r1;
    compute_point(pc1, tm, b, n, gi0, gi1, r0, r1);

    const int off0 = offs[b * 2 + 0];
    const int off1 = offs[b * 2 + 1];
    const int c0 = gi0 - off0;   // >= 0 by construction (offset is a true min)
    const int c1 = gi1 - off1;

    if (c0 < S2D && c1 < S2D) {
        const int pp0 = ((-off0) % 3 + 3) % 3;   // Python-style mod
        const int pp1 = ((-off1) % 3 + 3) % 3;
        const int i0 = (c0 - pp0) / 3;           // exact: c0 ≡ pp0 (mod 3)
        const int j0 = (c1 - pp1) / 3;
        float* dst = out + (((size_t)b * GRID_W + i0) * GRID_W + j0) * 3;
        atomicAdd(dst + 0, feat[((size_t)b * 3 + 0) * NPTS + n]);
        atomicAdd(dst + 1, feat[((size_t)b * 3 + 1) * NPTS + n]);
        atomicAdd(dst + 2, feat[((size_t)b * 3 + 2) * NPTS + n]);
    }
}

extern "C" void kernel_launch(void* const* d_in, const int* in_sizes, int n_in,
                              void* d_out, int out_size, void* d_ws, size_t ws_size,
                              hipStream_t stream) {
    const float* pc1  = (const float*)d_in[0];   // [64,3,8192]
    const float* feat = (const float*)d_in[1];   // [64,3,8192]
    const float* tm   = (const float*)d_in[2];   // [64,3,3]
    float* out = (float*)d_out;                  // [64,128,128,3]
    int*   offs = (int*)d_ws;                    // [64,2]

    // ws is poisoned 0xAA each call: init offsets to 0x7F7F7F7F (large positive)
    hipMemsetAsync(offs, 0x7F, NB * 2 * sizeof(int), stream);
    // output is scatter-accumulated: must start at zero every call
    hipMemsetAsync(out, 0, (size_t)out_size * sizeof(float), stream);

    dim3 grid(NPTS / 256, NB);
    offsets_kernel<<<grid, 256, 0, stream>>>(pc1, tm, offs);
    splat_kernel<<<grid, 256, 0, stream>>>(pc1, feat, tm, offs, out);
}

// Round 2
// 94.279 us; speedup vs baseline: 1.8811x; 1.8811x over previous
//
#include <hip/hip_runtime.h>
#include <math.h>

#define NB     64
#define NPTS   8192
#define S2D    384
#define GW     128
#define QROWS  32                 // rows of the 128-row grid per block
#define BLK    1024
#define PPT    (NPTS / BLK)       // 8 points per thread
#define ACCN   (QROWS * GW * 3)   // 12288 floats = 48 KB

// One block per (batch, quarter-of-grid). Phase 1: every block computes the
// per-batch offset min over all 8192 points (redundant across the 4 quarters,
// but compute is trivial). Phase 2: LDS-accumulate the points landing in this
// block's 32 grid rows. Phase 3: coalesced float4 writeout (fully overwrites
// the output -> no memset needed).
__global__ __launch_bounds__(1024) void fused_splat(const float* __restrict__ pc1,
                                                    const float* __restrict__ feat,
                                                    const float* __restrict__ tm,
                                                    float* __restrict__ out) {
    const int b   = blockIdx.x >> 2;
    const int q   = blockIdx.x & 3;
    const int tid = threadIdx.x;

    __shared__ __align__(16) float acc[ACCN];
    __shared__ int s_off[2];

    if (tid < 2) s_off[tid] = 0x7FFFFFFF;
#pragma unroll
    for (int i = 0; i < ACCN / BLK; i++)
        acc[tid + i * BLK] = 0.0f;

    float t[9];
#pragma unroll
    for (int i = 0; i < 9; i++) t[i] = tm[b * 9 + i];

    int gi0[PPT], gi1[PPT];
    int m0 = 0x7FFFFFFF, m1 = 0x7FFFFFFF;

    // ---- Phase 1: lattice computation (faithful fp32 semantics) + offset min
#pragma unroll
    for (int k = 0; k < PPT; k++) {
        const int n = tid + k * BLK;
        const float p0 = pc1[((size_t)b * 3 + 0) * NPTS + n];
        const float p1 = pc1[((size_t)b * 3 + 1) * NPTS + n];
        const float p2 = pc1[((size_t)b * 3 + 2) * NPTS + n];

        float g[3], v[3];
#pragma unroll
        for (int i = 0; i < 3; i++) {
            // fma-ascending 3-term dot, correctly-rounded /3, round-half-even
            float e  = fmaf(t[i*3+2], p2, fmaf(t[i*3+1], p1, t[i*3+0] * p0));
            float qq = __fdiv_rn(e, 3.0f);
            g[i] = rintf(qq) * 3.0f;      // exact in fp32 at this magnitude
            v[i] = e - g[i];              // exact (Sterbenz)
        }

        int rank[3];
#pragma unroll
        for (int i = 0; i < 3; i++) {
            int r = 0;
#pragma unroll
            for (int j = 0; j < 3; j++)
                if (v[j] > v[i] || (v[j] == v[i] && j < i)) r++;
            rank[i] = r;
        }

        const float rs_f = __fdiv_rn(g[0] + g[1] + g[2], 3.0f);  // exact int
        const int   rs   = (int)rs_f;

        int gi[2];
#pragma unroll
        for (int i = 0; i < 2; i++) {     // only lattice channels 0,1 matter
            const float rank_f = (float)rank[i];
            const bool cond = ((rank_f >= 3.0f - rs_f) && (rs_f > 0.0f)) ||
                              ((rank_f <  -rs_f)       && (rs_f < 0.0f));
            const float sign  = (rs_f > 0.0f ? -1.0f : 0.0f) + (rs_f < 0.0f ? 1.0f : 0.0f);
            const float shift = 3.0f * sign * (cond ? 1.0f : 0.0f);
            gi[i] = (int)(g[i] + shift);
            const int rfin = rank[i] + (int)shift + rs;
            // CANONICAL row-min is {0,-1,-2} for clamped rank (JAX gather clamps)
            const int cl = min(max(rfin, 0), 2);
            const int cand = gi[i] - cl;
            if (i == 0) m0 = min(m0, cand); else m1 = min(m1, cand);
        }
        gi0[k] = gi[0];
        gi1[k] = gi[1];
    }

    // wave64 min-reduction, then cross-wave via LDS atomicMin
#pragma unroll
    for (int off = 32; off > 0; off >>= 1) {
        m0 = min(m0, __shfl_down(m0, off));
        m1 = min(m1, __shfl_down(m1, off));
    }
    if ((tid & 63) == 0) {
        atomicMin(&s_off[0], m0);
        atomicMin(&s_off[1], m1);
    }
    __syncthreads();

    const int off0 = s_off[0], off1 = s_off[1];
    const int pp0 = ((-off0) % 3 + 3) % 3;
    const int pp1 = ((-off1) % 3 + 3) % 3;
    const int rlo = q * QROWS, rhi = rlo + QROWS;

    // ---- Phase 2: LDS scatter-accumulate this block's quarter
#pragma unroll
    for (int k = 0; k < PPT; k++) {
        const int n  = tid + k * BLK;
        const int c0 = gi0[k] - off0;     // >= 0 (offset is a true min)
        const int c1 = gi1[k] - off1;
        if (c0 < S2D && c1 < S2D) {
            const int i0 = (c0 - pp0) / 3;   // exact: c0 ≡ pp0 (mod 3)
            if (i0 >= rlo && i0 < rhi) {
                const int j0 = (c1 - pp1) / 3;
                float* dst = acc + (((i0 - rlo) * GW) + j0) * 3;
                atomicAdd(dst + 0, feat[((size_t)b * 3 + 0) * NPTS + n]);
                atomicAdd(dst + 1, feat[((size_t)b * 3 + 1) * NPTS + n]);
                atomicAdd(dst + 2, feat[((size_t)b * 3 + 2) * NPTS + n]);
            }
        }
    }
    __syncthreads();

    // ---- Phase 3: coalesced writeout (fully overwrites -> no memset)
    float4* __restrict__ dst4 = (float4*)(out + ((size_t)b * GW + rlo) * GW * 3);
    const float4* __restrict__ src4 = (const float4*)acc;
#pragma unroll
    for (int i = 0; i < ACCN / (4 * BLK); i++)   // 3 float4 per thread
        dst4[tid + i * BLK] = src4[tid + i * BLK];
}

extern "C" void kernel_launch(void* const* d_in, const int* in_sizes, int n_in,
                              void* d_out, int out_size, void* d_ws, size_t ws_size,
                              hipStream_t stream) {
    const float* pc1  = (const float*)d_in[0];   // [64,3,8192]
    const float* feat = (const float*)d_in[1];   // [64,3,8192]
    const float* tm   = (const float*)d_in[2];   // [64,3,3]
    float* out = (float*)d_out;                  // [64,128,128,3]

    fused_splat<<<NB * 4, BLK, 0, stream>>>(pc1, feat, tm, out);
}